// Round 12
// baseline (70.420 us; speedup 1.0000x reference)
//
#include <hip/hip_runtime.h>
#include <cmath>

// Bokeh render, gather form:
// out[b,c,y,x] = sum_{dy,dx in [-4,4]} w * img[b,c,y-dy,x-dx] / sum w
// w = sigmoid(8*(r_src - dist)) / max(pi*r_src^2,1);  r = |defocus| in [0,4).
// Window mask dropped (outside-window w <= sigma(-8): output shift <2e-5).
// OOB sources exact via Iv=0.
//
// R12: occupancy x2 on the R10 structure. R11 diagnostic: main-loop marginal
// 10.8us (VALU ~8.5, LDS-pipe ~7.8 -- separate pipes, already ~80%
// overlapped), staging+overhead 8.6us, VALUBusy 64-68%. Conflict rate is
// ~17-20cyc/b128 INVARIANT across 8/16-lane, f32/bf16 layouts (R3-R11
// ledger) => inherent to wave64 b128 tile reads, not swizzle-fixable; it
// scales only with instr count. Lever: more waves to push VALUBusy -> ~90%.
//  - 1024 thr = 4 dy-groups x 256: {0-1},{2-3},{4-5},{6-8} (last adder
//    gets 3 rows to overlap the serialized combine rounds).
//  - grid 8x32x2 = 512 blocks = 2 blk/CU -> 2048 thr/CU = 100% nominal.
//  - sequential pbuf combine (g1 w; bar; g2 +=; bar; g3 +=; bar; g0 out),
//    pbuf[256][20] = 20KB; total LDS 41.6KB -> 2 blocks/CU fits.
//  - __launch_bounds__(1024,8) caps VGPR at 64 (R10 measured 56).

#define HH 512
#define WW 512
#define NB 2
#define TW 64                     // tile width (16 quads, zero waste)
#define TH 16                     // tile height
#define HALO 4
#define SROWS (TH + 2 * HALO)     // 24
#define LW 72                     // 4 + 64 + 4 = exactly 72 dwords/row

__device__ __forceinline__ unsigned rtne_hi(float v) {
  // bf16 round-to-nearest-even, result in HIGH 16 bits (low 16 zero).
  unsigned u = __float_as_uint(v);
  u = u + 0x7FFFu + ((u >> 16) & 1u);
  return u & 0xFFFF0000u;
}

__global__ __launch_bounds__(1024, 8) void bokeh_gather(
    const float* __restrict__ img,
    const float* __restrict__ def,
    float* __restrict__ out)
{
  __shared__ __align__(16) unsigned sX[SROWS][LW];  // G(hi) | Iv(lo)   bf16
  __shared__ __align__(16) unsigned sY[SROWS][LW];  // c0(hi) | c1(lo)  bf16
  __shared__ __align__(16) unsigned sZ[SROWS][LW];  // c2 truncated f32
  __shared__ float sFd[9][12];                      // exp(8*dist(dy,dx))
  __shared__ __align__(16) float pbuf[256][20];     // partial-sum exchange

  const int tid = threadIdx.x;
  const int s   = tid >> 8;      // dy-group 0..3
  const int t   = tid & 255;
  const int tx  = t & 15;        // 16 lanes * 4 px = 64 cols
  const int ty  = t >> 4;        // 16 rows
  const int bx = blockIdx.x * TW;
  const int by = blockIdx.y * TH;
  const int b  = blockIdx.z;

  if (tid < 81) {
    int dyi = tid / 9, dxi = tid - dyi * 9;
    int dyo = dyi - 4, dxo = dxi - 4;
    float d2 = (float)(dyo * dyo + dxo * dxo);
    sFd[dyi][dxi] = __expf(8.0f * sqrtf(d2));
  }

  const float* dpt = def + b * (HH * WW);
  const float* ipt = img + b * (3 * HH * WW);

  // Stage halo'd tile: 24 rows x 72 cols = 1728 px / 1024 thr = 2 iters.
  // OOB -> zeros => w = 0 exactly.
  for (int idx = tid; idx < SROWS * LW; idx += 1024) {
    int ly = idx / LW;
    int lx = idx - ly * LW;
    int sy = by - HALO + ly;
    int sx = bx - HALO + lx;
    unsigned X = 0u, Y = 0u, Z = 0u;
    if ((unsigned)sy < (unsigned)HH && (unsigned)sx < (unsigned)WW) {
      int o = sy * WW + sx;
      float r = fabsf(dpt[o]);
      float G  = __expf(-8.0f * r);
      float iv = __builtin_amdgcn_rcpf(fmaxf(3.14159265358979f * r * r, 1.0f));
      X = rtne_hi(G) | (rtne_hi(iv) >> 16);
      Y = rtne_hi(ipt[o]) | (rtne_hi(ipt[o + HH * WW]) >> 16);
      Z = __float_as_uint(ipt[o + 2 * HH * WW]) & 0xFFFF0000u;
    }
    sX[ly][lx] = X;
    sY[ly][lx] = Y;
    sZ[ly][lx] = Z;
  }
  __syncthreads();

  float wsum[4] = {0.f, 0.f, 0.f, 0.f};
  float ac0[4]  = {0.f, 0.f, 0.f, 0.f};
  float ac1[4]  = {0.f, 0.f, 0.f, 0.f};
  float ac2[4]  = {0.f, 0.f, 0.f, 0.f};

  const int col0 = 4 * tx;       // window start col (16B aligned)
  // dy ranges per group: g0 {0,1}, g1 {2,3}, g2 {4,5}, g3 {6,7,8}.
  const int dy0 = (s == 0) ? 0 : (s == 1) ? 2 : (s == 2) ? 4 : 6;
  const int dy1 = (s == 0) ? 2 : (s == 1) ? 4 : (s == 2) ? 6 : 9;

  #pragma unroll 1
  for (int dy = dy0; dy < dy1; ++dy) {
    const int sr = ty + dy;
    float fdr[9];
    #pragma unroll
    for (int x = 0; x < 9; ++x) fdr[x] = sFd[dy][x];

    unsigned Xv[12], Yv[12], Zv[12];
    #pragma unroll
    for (int q = 0; q < 3; ++q) {
      *(uint4*)&Xv[4 * q] = *(const uint4*)(&sX[sr][col0] + 4 * q);
      *(uint4*)&Yv[4 * q] = *(const uint4*)(&sY[sr][col0] + 4 * q);
      *(uint4*)&Zv[4 * q] = *(const uint4*)(&sZ[sr][col0] + 4 * q);
    }
    float Gv[12], Iv[12], C0[12], C1[12];
    #pragma unroll
    for (int j = 0; j < 12; ++j) {
      Gv[j] = __uint_as_float(Xv[j] & 0xFFFF0000u);
      Iv[j] = __uint_as_float(Xv[j] << 16);
      C0[j] = __uint_as_float(Yv[j] & 0xFFFF0000u);
      C1[j] = __uint_as_float(Yv[j] << 16);
    }

    #pragma unroll
    for (int k = 0; k < 4; ++k) {
      #pragma unroll
      for (int j = k; j < k + 9; ++j) {
        const int xi = j - k;                      // compile-time
        float tden = fmaf(Gv[j], fdr[xi], 1.0f);   // 1 + e^{-8r} e^{8d}
        float w = __builtin_amdgcn_rcpf(tden) * Iv[j];
        wsum[k] += w;
        ac0[k] = fmaf(w, C0[j], ac0[k]);
        ac1[k] = fmaf(w, C1[j], ac1[k]);
        ac2[k] = fmaf(w, __uint_as_float(Zv[j]), ac2[k]);
      }
    }
  }

  // Sequential partial-sum combine through pbuf (g3 computes 3 rows while
  // g1/g2 do their rounds -> serialization overlapped).
  if (s == 1) {
    *(float4*)&pbuf[t][0]  = make_float4(wsum[0], wsum[1], wsum[2], wsum[3]);
    *(float4*)&pbuf[t][4]  = make_float4(ac0[0], ac0[1], ac0[2], ac0[3]);
    *(float4*)&pbuf[t][8]  = make_float4(ac1[0], ac1[1], ac1[2], ac1[3]);
    *(float4*)&pbuf[t][12] = make_float4(ac2[0], ac2[1], ac2[2], ac2[3]);
  }
  __syncthreads();
  if (s == 2) {
    float4 v0 = *(const float4*)&pbuf[t][0];
    float4 v1 = *(const float4*)&pbuf[t][4];
    float4 v2 = *(const float4*)&pbuf[t][8];
    float4 v3 = *(const float4*)&pbuf[t][12];
    *(float4*)&pbuf[t][0]  = make_float4(v0.x + wsum[0], v0.y + wsum[1], v0.z + wsum[2], v0.w + wsum[3]);
    *(float4*)&pbuf[t][4]  = make_float4(v1.x + ac0[0], v1.y + ac0[1], v1.z + ac0[2], v1.w + ac0[3]);
    *(float4*)&pbuf[t][8]  = make_float4(v2.x + ac1[0], v2.y + ac1[1], v2.z + ac1[2], v2.w + ac1[3]);
    *(float4*)&pbuf[t][12] = make_float4(v3.x + ac2[0], v3.y + ac2[1], v3.z + ac2[2], v3.w + ac2[3]);
  }
  __syncthreads();
  if (s == 3) {
    float4 v0 = *(const float4*)&pbuf[t][0];
    float4 v1 = *(const float4*)&pbuf[t][4];
    float4 v2 = *(const float4*)&pbuf[t][8];
    float4 v3 = *(const float4*)&pbuf[t][12];
    *(float4*)&pbuf[t][0]  = make_float4(v0.x + wsum[0], v0.y + wsum[1], v0.z + wsum[2], v0.w + wsum[3]);
    *(float4*)&pbuf[t][4]  = make_float4(v1.x + ac0[0], v1.y + ac0[1], v1.z + ac0[2], v1.w + ac0[3]);
    *(float4*)&pbuf[t][8]  = make_float4(v2.x + ac1[0], v2.y + ac1[1], v2.z + ac1[2], v2.w + ac1[3]);
    *(float4*)&pbuf[t][12] = make_float4(v3.x + ac2[0], v3.y + ac2[1], v3.z + ac2[2], v3.w + ac2[3]);
  }
  __syncthreads();
  if (s == 0) {
    float4 v0 = *(const float4*)&pbuf[t][0];
    float4 v1 = *(const float4*)&pbuf[t][4];
    float4 v2 = *(const float4*)&pbuf[t][8];
    float4 v3 = *(const float4*)&pbuf[t][12];
    wsum[0] += v0.x; wsum[1] += v0.y; wsum[2] += v0.z; wsum[3] += v0.w;
    ac0[0] += v1.x; ac0[1] += v1.y; ac0[2] += v1.z; ac0[3] += v1.w;
    ac1[0] += v2.x; ac1[1] += v2.y; ac1[2] += v2.z; ac1[3] += v2.w;
    ac2[0] += v3.x; ac2[1] += v3.y; ac2[2] += v3.z; ac2[3] += v3.w;

    const int oy = by + ty;
    const int ox = bx + col0;
    float rw[4];
    #pragma unroll
    for (int k = 0; k < 4; ++k) rw[k] = __builtin_amdgcn_rcpf(wsum[k]);

    float* op0 = out + ((b * 3 + 0) * HH + oy) * WW + ox;
    float* op1 = out + ((b * 3 + 1) * HH + oy) * WW + ox;
    float* op2 = out + ((b * 3 + 2) * HH + oy) * WW + ox;
    float4 o0, o1, o2;
    o0.x = ac0[0] * rw[0]; o0.y = ac0[1] * rw[1]; o0.z = ac0[2] * rw[2]; o0.w = ac0[3] * rw[3];
    o1.x = ac1[0] * rw[0]; o1.y = ac1[1] * rw[1]; o1.z = ac1[2] * rw[2]; o1.w = ac1[3] * rw[3];
    o2.x = ac2[0] * rw[0]; o2.y = ac2[1] * rw[1]; o2.z = ac2[2] * rw[2]; o2.w = ac2[3] * rw[3];
    *(float4*)op0 = o0;
    *(float4*)op1 = o1;
    *(float4*)op2 = o2;
  }
}

extern "C" void kernel_launch(void* const* d_in, const int* in_sizes, int n_in,
                              void* d_out, int out_size, void* d_ws, size_t ws_size,
                              hipStream_t stream) {
  const float* img = (const float*)d_in[0];   // (2,3,512,512) f32
  const float* def = (const float*)d_in[1];   // (2,1,512,512) f32
  float* out = (float*)d_out;                 // (2,3,512,512) f32

  dim3 grid(WW / TW, HH / TH, NB);            // 8 x 32 x 2 = 512 blocks = 2/CU
  dim3 block(1024);
  hipLaunchKernelGGL(bokeh_gather, grid, block, 0, stream, img, def, out);
}

// Round 13
// 56.745 us; speedup vs baseline: 1.2410x; 1.2410x over previous
//
#include <hip/hip_runtime.h>
#include <cmath>

// Bokeh render, gather form:
// out[b,c,y,x] = sum_{dy,dx in [-4,4]} w * img[b,c,y-dy,x-dx] / sum w
// w = sigmoid(8*(r_src - dist)) / max(pi*r_src^2,1);  r = |defocus| in [0,4).
// Window mask dropped (outside-window w <= sigma(-8): output shift <2e-5).
// OOB sources: J=1e30, H=0 -> w ~= 1e-30 (effectively exact zero).
//
// R13: 8 waves/SIMD done *without* a VGPR cap squeeze. R12's 70us was a
// forced spill: __launch_bounds__(1024,8) capped VGPR at 32 vs ~56 needed
// (FETCH 100MB / WRITE 210MB scratch, VALUBusy 15%). Same occupancy target,
// safe geometry: tile 32x16, 512-thr block = 4 dy-groups x 128 thr
// ({0,1},{2,3},{4,5},{6,7,8}), grid 16x32x2 = 1024 blocks = 4 blk/CU ->
// 2048 thr/CU = 8 waves/SIMD. launch_bounds(512,8) -> cap 64 >= 56 measured.
// LDS 22KB x 4 blocks = 88KB < 160KB. Plus J/H fold: w = rcp(fma(H,Fd,J)),
// J = max(pi r^2,1), H = exp(-8r)*J -- kills the per-tap Iv multiply.
// R11 baseline counters: VALUBusy 64-68% @ 4 waves/SIMD, main 10.8us,
// staging+overhead 8.6us.

#define HH 512
#define WW 512
#define NB 2
#define TW 32                     // tile width (8 quads)
#define TH 16                     // tile height
#define HALO 4
#define SROWS (TH + 2 * HALO)     // 24
#define LW 40                     // 4 + 32 + 4 dwords per row

__device__ __forceinline__ unsigned rtne_hi(float v) {
  // bf16 round-to-nearest-even, result in HIGH 16 bits (low 16 zero).
  unsigned u = __float_as_uint(v);
  u = u + 0x7FFFu + ((u >> 16) & 1u);
  return u & 0xFFFF0000u;
}

__global__ __launch_bounds__(512, 8) void bokeh_gather(
    const float* __restrict__ img,
    const float* __restrict__ def,
    float* __restrict__ out)
{
  __shared__ __align__(16) unsigned sX[SROWS][LW];  // J(hi) | H(lo)   bf16
  __shared__ __align__(16) unsigned sY[SROWS][LW];  // c0(hi) | c1(lo) bf16
  __shared__ __align__(16) unsigned sZ[SROWS][LW];  // c2 truncated f32
  __shared__ float sFd[9][12];                      // exp(8*dist(dy,dx))
  __shared__ __align__(16) float pbuf[128][20];     // partial-sum exchange

  const int tid = threadIdx.x;
  const int s   = tid >> 7;      // dy-group 0..3
  const int t   = tid & 127;
  const int tx  = t & 7;         // 8 lanes * 4 px = 32 cols
  const int ty  = t >> 3;        // 16 rows
  const int bx = blockIdx.x * TW;
  const int by = blockIdx.y * TH;
  const int b  = blockIdx.z;

  if (tid < 81) {
    int dyi = tid / 9, dxi = tid - dyi * 9;
    int dyo = dyi - 4, dxo = dxi - 4;
    float d2 = (float)(dyo * dyo + dxo * dxo);
    sFd[dyi][dxi] = __expf(8.0f * sqrtf(d2));
  }

  const float* dpt = def + b * (HH * WW);
  const float* ipt = img + b * (3 * HH * WW);

  // Stage halo'd tile: 24 rows x 40 cols = 960 entries / 512 thr = 2 iters.
  for (int idx = tid; idx < SROWS * LW; idx += 512) {
    int ly = idx / LW;
    int lx = idx - ly * LW;
    int sy = by - HALO + ly;
    int sx = bx - HALO + lx;
    unsigned X, Y = 0u, Z = 0u;
    if ((unsigned)sy < (unsigned)HH && (unsigned)sx < (unsigned)WW) {
      int o = sy * WW + sx;
      float r = fabsf(dpt[o]);
      float J  = fmaxf(3.14159265358979f * r * r, 1.0f);
      float Hv = __expf(-8.0f * r) * J;
      X = rtne_hi(J) | (rtne_hi(Hv) >> 16);
      Y = rtne_hi(ipt[o]) | (rtne_hi(ipt[o + HH * WW]) >> 16);
      Z = __float_as_uint(ipt[o + 2 * HH * WW]) & 0xFFFF0000u;
    } else {
      X = rtne_hi(1e30f);        // J huge, H = 0 -> w ~= 1e-30, channels 0
    }
    sX[ly][lx] = X;
    sY[ly][lx] = Y;
    sZ[ly][lx] = Z;
  }
  __syncthreads();

  float wsum[4] = {0.f, 0.f, 0.f, 0.f};
  float ac0[4]  = {0.f, 0.f, 0.f, 0.f};
  float ac1[4]  = {0.f, 0.f, 0.f, 0.f};
  float ac2[4]  = {0.f, 0.f, 0.f, 0.f};

  const int col0 = 4 * tx;       // window start col (16B aligned)
  // dy ranges: g0 {0,1}, g1 {2,3}, g2 {4,5}, g3 {6,7,8}.
  const int dy0 = 2 * s;
  const int dy1 = (s == 3) ? 9 : (2 * s + 2);

  #pragma unroll 1
  for (int dy = dy0; dy < dy1; ++dy) {
    const int sr = ty + dy;
    float fdr[9];
    #pragma unroll
    for (int x = 0; x < 9; ++x) fdr[x] = sFd[dy][x];

    unsigned Xv[12], Yv[12], Zv[12];
    #pragma unroll
    for (int q = 0; q < 3; ++q) {
      *(uint4*)&Xv[4 * q] = *(const uint4*)(&sX[sr][col0] + 4 * q);
      *(uint4*)&Yv[4 * q] = *(const uint4*)(&sY[sr][col0] + 4 * q);
      *(uint4*)&Zv[4 * q] = *(const uint4*)(&sZ[sr][col0] + 4 * q);
    }
    float Jv[12], Hv[12], C0[12], C1[12];
    #pragma unroll
    for (int j = 0; j < 12; ++j) {
      Jv[j] = __uint_as_float(Xv[j] & 0xFFFF0000u);
      Hv[j] = __uint_as_float(Xv[j] << 16);
      C0[j] = __uint_as_float(Yv[j] & 0xFFFF0000u);
      C1[j] = __uint_as_float(Yv[j] << 16);
    }

    #pragma unroll
    for (int k = 0; k < 4; ++k) {
      #pragma unroll
      for (int j = k; j < k + 9; ++j) {
        const int xi = j - k;                      // compile-time
        float tden = fmaf(Hv[j], fdr[xi], Jv[j]);  // J + e^{-8r}J e^{8d}
        float w = __builtin_amdgcn_rcpf(tden);     // = Iv * sigmoid
        wsum[k] += w;
        ac0[k] = fmaf(w, C0[j], ac0[k]);
        ac1[k] = fmaf(w, C1[j], ac1[k]);
        ac2[k] = fmaf(w, __uint_as_float(Zv[j]), ac2[k]);
      }
    }
  }

  // Sequential combine through pbuf: g1 write, g2 +=, g3 +=, g0 finalize.
  if (s == 1) {
    *(float4*)&pbuf[t][0]  = make_float4(wsum[0], wsum[1], wsum[2], wsum[3]);
    *(float4*)&pbuf[t][4]  = make_float4(ac0[0], ac0[1], ac0[2], ac0[3]);
    *(float4*)&pbuf[t][8]  = make_float4(ac1[0], ac1[1], ac1[2], ac1[3]);
    *(float4*)&pbuf[t][12] = make_float4(ac2[0], ac2[1], ac2[2], ac2[3]);
  }
  __syncthreads();
  if (s == 2) {
    float4 v0 = *(const float4*)&pbuf[t][0];
    float4 v1 = *(const float4*)&pbuf[t][4];
    float4 v2 = *(const float4*)&pbuf[t][8];
    float4 v3 = *(const float4*)&pbuf[t][12];
    *(float4*)&pbuf[t][0]  = make_float4(v0.x + wsum[0], v0.y + wsum[1], v0.z + wsum[2], v0.w + wsum[3]);
    *(float4*)&pbuf[t][4]  = make_float4(v1.x + ac0[0], v1.y + ac0[1], v1.z + ac0[2], v1.w + ac0[3]);
    *(float4*)&pbuf[t][8]  = make_float4(v2.x + ac1[0], v2.y + ac1[1], v2.z + ac1[2], v2.w + ac1[3]);
    *(float4*)&pbuf[t][12] = make_float4(v3.x + ac2[0], v3.y + ac2[1], v3.z + ac2[2], v3.w + ac2[3]);
  }
  __syncthreads();
  if (s == 3) {
    float4 v0 = *(const float4*)&pbuf[t][0];
    float4 v1 = *(const float4*)&pbuf[t][4];
    float4 v2 = *(const float4*)&pbuf[t][8];
    float4 v3 = *(const float4*)&pbuf[t][12];
    *(float4*)&pbuf[t][0]  = make_float4(v0.x + wsum[0], v0.y + wsum[1], v0.z + wsum[2], v0.w + wsum[3]);
    *(float4*)&pbuf[t][4]  = make_float4(v1.x + ac0[0], v1.y + ac0[1], v1.z + ac0[2], v1.w + ac0[3]);
    *(float4*)&pbuf[t][8]  = make_float4(v2.x + ac1[0], v2.y + ac1[1], v2.z + ac1[2], v2.w + ac1[3]);
    *(float4*)&pbuf[t][12] = make_float4(v3.x + ac2[0], v3.y + ac2[1], v3.z + ac2[2], v3.w + ac2[3]);
  }
  __syncthreads();
  if (s == 0) {
    float4 v0 = *(const float4*)&pbuf[t][0];
    float4 v1 = *(const float4*)&pbuf[t][4];
    float4 v2 = *(const float4*)&pbuf[t][8];
    float4 v3 = *(const float4*)&pbuf[t][12];
    wsum[0] += v0.x; wsum[1] += v0.y; wsum[2] += v0.z; wsum[3] += v0.w;
    ac0[0] += v1.x; ac0[1] += v1.y; ac0[2] += v1.z; ac0[3] += v1.w;
    ac1[0] += v2.x; ac1[1] += v2.y; ac1[2] += v2.z; ac1[3] += v2.w;
    ac2[0] += v3.x; ac2[1] += v3.y; ac2[2] += v3.z; ac2[3] += v3.w;

    const int oy = by + ty;
    const int ox = bx + col0;
    float rw[4];
    #pragma unroll
    for (int k = 0; k < 4; ++k) rw[k] = __builtin_amdgcn_rcpf(wsum[k]);

    float* op0 = out + ((b * 3 + 0) * HH + oy) * WW + ox;
    float* op1 = out + ((b * 3 + 1) * HH + oy) * WW + ox;
    float* op2 = out + ((b * 3 + 2) * HH + oy) * WW + ox;
    float4 o0, o1, o2;
    o0.x = ac0[0] * rw[0]; o0.y = ac0[1] * rw[1]; o0.z = ac0[2] * rw[2]; o0.w = ac0[3] * rw[3];
    o1.x = ac1[0] * rw[0]; o1.y = ac1[1] * rw[1]; o1.z = ac1[2] * rw[2]; o1.w = ac1[3] * rw[3];
    o2.x = ac2[0] * rw[0]; o2.y = ac2[1] * rw[1]; o2.z = ac2[2] * rw[2]; o2.w = ac2[3] * rw[3];
    *(float4*)op0 = o0;
    *(float4*)op1 = o1;
    *(float4*)op2 = o2;
  }
}

extern "C" void kernel_launch(void* const* d_in, const int* in_sizes, int n_in,
                              void* d_out, int out_size, void* d_ws, size_t ws_size,
                              hipStream_t stream) {
  const float* img = (const float*)d_in[0];   // (2,3,512,512) f32
  const float* def = (const float*)d_in[1];   // (2,1,512,512) f32
  float* out = (float*)d_out;                 // (2,3,512,512) f32

  dim3 grid(WW / TW, HH / TH, NB);            // 16 x 32 x 2 = 1024 = 4/CU
  dim3 block(512);
  hipLaunchKernelGGL(bokeh_gather, grid, block, 0, stream, img, def, out);
}

// Round 14
// 20.268 us; speedup vs baseline: 3.4744x; 2.7997x over previous
//
#include <hip/hip_runtime.h>
#include <cmath>

// Bokeh render, gather form:
// out[b,c,y,x] = sum_{dy,dx in [-4,4]} w * img[b,c,y-dy,x-dx] / sum w
// w = sigmoid(8*(r_src - dist)) / max(pi*r_src^2,1);  r = |defocus| in [0,4).
// Window mask dropped (outside-window w <= sigma(-8): output shift <2e-5).
// OOB sources: J=1e30, H=0 -> w ~= 1e-30 (effectively exact zero).
//
// R14 = R13 geometry WITHOUT the register cap. R12 (1024,8) and R13 (512,8)
// both spilled because declaring 8 waves/EU makes the compiler cap VGPR at
// 32 (< the ~56 this body needs). HW occupancy follows ACTUAL VGPR use:
// 56 <= 64 -> 8 waves/SIMD scheduled automatically, provided the grid has
// >= 4 blocks/CU. So: launch_bounds(512,4) (cap 128, natural ~56), grid
// 16x32x2 = 1024 blocks = 4 blk/CU, LDS 22KB*4 = 88KB < 160KB.
// Taps keep the R13 J/H fold: w = rcp(fma(H, Fd, J)), J = max(pi r^2,1),
// H = exp(-8r)*J (numerics verified in R13: absmax 3.9e-3).

#define HH 512
#define WW 512
#define NB 2
#define TW 32                     // tile width (8 quads)
#define TH 16                     // tile height
#define HALO 4
#define SROWS (TH + 2 * HALO)     // 24
#define LW 40                     // 4 + 32 + 4 dwords per row

__device__ __forceinline__ unsigned rtne_hi(float v) {
  // bf16 round-to-nearest-even, result in HIGH 16 bits (low 16 zero).
  unsigned u = __float_as_uint(v);
  u = u + 0x7FFFu + ((u >> 16) & 1u);
  return u & 0xFFFF0000u;
}

__global__ __launch_bounds__(512, 4) void bokeh_gather(
    const float* __restrict__ img,
    const float* __restrict__ def,
    float* __restrict__ out)
{
  __shared__ __align__(16) unsigned sX[SROWS][LW];  // J(hi) | H(lo)   bf16
  __shared__ __align__(16) unsigned sY[SROWS][LW];  // c0(hi) | c1(lo) bf16
  __shared__ __align__(16) unsigned sZ[SROWS][LW];  // c2 truncated f32
  __shared__ float sFd[9][12];                      // exp(8*dist(dy,dx))
  __shared__ __align__(16) float pbuf[128][20];     // partial-sum exchange

  const int tid = threadIdx.x;
  const int s   = tid >> 7;      // dy-group 0..3
  const int t   = tid & 127;
  const int tx  = t & 7;         // 8 lanes * 4 px = 32 cols
  const int ty  = t >> 3;        // 16 rows
  const int bx = blockIdx.x * TW;
  const int by = blockIdx.y * TH;
  const int b  = blockIdx.z;

  if (tid < 81) {
    int dyi = tid / 9, dxi = tid - dyi * 9;
    int dyo = dyi - 4, dxo = dxi - 4;
    float d2 = (float)(dyo * dyo + dxo * dxo);
    sFd[dyi][dxi] = __expf(8.0f * sqrtf(d2));
  }

  const float* dpt = def + b * (HH * WW);
  const float* ipt = img + b * (3 * HH * WW);

  // Stage halo'd tile: 24 rows x 40 cols = 960 entries / 512 thr = 2 iters.
  for (int idx = tid; idx < SROWS * LW; idx += 512) {
    int ly = idx / LW;
    int lx = idx - ly * LW;
    int sy = by - HALO + ly;
    int sx = bx - HALO + lx;
    unsigned X, Y = 0u, Z = 0u;
    if ((unsigned)sy < (unsigned)HH && (unsigned)sx < (unsigned)WW) {
      int o = sy * WW + sx;
      float r = fabsf(dpt[o]);
      float J  = fmaxf(3.14159265358979f * r * r, 1.0f);
      float Hv = __expf(-8.0f * r) * J;
      X = rtne_hi(J) | (rtne_hi(Hv) >> 16);
      Y = rtne_hi(ipt[o]) | (rtne_hi(ipt[o + HH * WW]) >> 16);
      Z = __float_as_uint(ipt[o + 2 * HH * WW]) & 0xFFFF0000u;
    } else {
      X = rtne_hi(1e30f);        // J huge, H = 0 -> w ~= 1e-30, channels 0
    }
    sX[ly][lx] = X;
    sY[ly][lx] = Y;
    sZ[ly][lx] = Z;
  }
  __syncthreads();

  float wsum[4] = {0.f, 0.f, 0.f, 0.f};
  float ac0[4]  = {0.f, 0.f, 0.f, 0.f};
  float ac1[4]  = {0.f, 0.f, 0.f, 0.f};
  float ac2[4]  = {0.f, 0.f, 0.f, 0.f};

  const int col0 = 4 * tx;       // window start col (16B aligned)
  // dy ranges: g0 {0,1}, g1 {2,3}, g2 {4,5}, g3 {6,7,8}.
  const int dy0 = 2 * s;
  const int dy1 = (s == 3) ? 9 : (2 * s + 2);

  #pragma unroll 1
  for (int dy = dy0; dy < dy1; ++dy) {
    const int sr = ty + dy;
    float fdr[9];
    #pragma unroll
    for (int x = 0; x < 9; ++x) fdr[x] = sFd[dy][x];

    unsigned Xv[12], Yv[12], Zv[12];
    #pragma unroll
    for (int q = 0; q < 3; ++q) {
      *(uint4*)&Xv[4 * q] = *(const uint4*)(&sX[sr][col0] + 4 * q);
      *(uint4*)&Yv[4 * q] = *(const uint4*)(&sY[sr][col0] + 4 * q);
      *(uint4*)&Zv[4 * q] = *(const uint4*)(&sZ[sr][col0] + 4 * q);
    }
    float Jv[12], Hv[12], C0[12], C1[12];
    #pragma unroll
    for (int j = 0; j < 12; ++j) {
      Jv[j] = __uint_as_float(Xv[j] & 0xFFFF0000u);
      Hv[j] = __uint_as_float(Xv[j] << 16);
      C0[j] = __uint_as_float(Yv[j] & 0xFFFF0000u);
      C1[j] = __uint_as_float(Yv[j] << 16);
    }

    #pragma unroll
    for (int k = 0; k < 4; ++k) {
      #pragma unroll
      for (int j = k; j < k + 9; ++j) {
        const int xi = j - k;                      // compile-time
        float tden = fmaf(Hv[j], fdr[xi], Jv[j]);  // J + e^{-8r}J e^{8d}
        float w = __builtin_amdgcn_rcpf(tden);     // = Iv * sigmoid
        wsum[k] += w;
        ac0[k] = fmaf(w, C0[j], ac0[k]);
        ac1[k] = fmaf(w, C1[j], ac1[k]);
        ac2[k] = fmaf(w, __uint_as_float(Zv[j]), ac2[k]);
      }
    }
  }

  // Sequential combine through pbuf: g1 write, g2 +=, g3 +=, g0 finalize.
  if (s == 1) {
    *(float4*)&pbuf[t][0]  = make_float4(wsum[0], wsum[1], wsum[2], wsum[3]);
    *(float4*)&pbuf[t][4]  = make_float4(ac0[0], ac0[1], ac0[2], ac0[3]);
    *(float4*)&pbuf[t][8]  = make_float4(ac1[0], ac1[1], ac1[2], ac1[3]);
    *(float4*)&pbuf[t][12] = make_float4(ac2[0], ac2[1], ac2[2], ac2[3]);
  }
  __syncthreads();
  if (s == 2) {
    float4 v0 = *(const float4*)&pbuf[t][0];
    float4 v1 = *(const float4*)&pbuf[t][4];
    float4 v2 = *(const float4*)&pbuf[t][8];
    float4 v3 = *(const float4*)&pbuf[t][12];
    *(float4*)&pbuf[t][0]  = make_float4(v0.x + wsum[0], v0.y + wsum[1], v0.z + wsum[2], v0.w + wsum[3]);
    *(float4*)&pbuf[t][4]  = make_float4(v1.x + ac0[0], v1.y + ac0[1], v1.z + ac0[2], v1.w + ac0[3]);
    *(float4*)&pbuf[t][8]  = make_float4(v2.x + ac1[0], v2.y + ac1[1], v2.z + ac1[2], v2.w + ac1[3]);
    *(float4*)&pbuf[t][12] = make_float4(v3.x + ac2[0], v3.y + ac2[1], v3.z + ac2[2], v3.w + ac2[3]);
  }
  __syncthreads();
  if (s == 3) {
    float4 v0 = *(const float4*)&pbuf[t][0];
    float4 v1 = *(const float4*)&pbuf[t][4];
    float4 v2 = *(const float4*)&pbuf[t][8];
    float4 v3 = *(const float4*)&pbuf[t][12];
    *(float4*)&pbuf[t][0]  = make_float4(v0.x + wsum[0], v0.y + wsum[1], v0.z + wsum[2], v0.w + wsum[3]);
    *(float4*)&pbuf[t][4]  = make_float4(v1.x + ac0[0], v1.y + ac0[1], v1.z + ac0[2], v1.w + ac0[3]);
    *(float4*)&pbuf[t][8]  = make_float4(v2.x + ac1[0], v2.y + ac1[1], v2.z + ac1[2], v2.w + ac1[3]);
    *(float4*)&pbuf[t][12] = make_float4(v3.x + ac2[0], v3.y + ac2[1], v3.z + ac2[2], v3.w + ac2[3]);
  }
  __syncthreads();
  if (s == 0) {
    float4 v0 = *(const float4*)&pbuf[t][0];
    float4 v1 = *(const float4*)&pbuf[t][4];
    float4 v2 = *(const float4*)&pbuf[t][8];
    float4 v3 = *(const float4*)&pbuf[t][12];
    wsum[0] += v0.x; wsum[1] += v0.y; wsum[2] += v0.z; wsum[3] += v0.w;
    ac0[0] += v1.x; ac0[1] += v1.y; ac0[2] += v1.z; ac0[3] += v1.w;
    ac1[0] += v2.x; ac1[1] += v2.y; ac1[2] += v2.z; ac1[3] += v2.w;
    ac2[0] += v3.x; ac2[1] += v3.y; ac2[2] += v3.z; ac2[3] += v3.w;

    const int oy = by + ty;
    const int ox = bx + col0;
    float rw[4];
    #pragma unroll
    for (int k = 0; k < 4; ++k) rw[k] = __builtin_amdgcn_rcpf(wsum[k]);

    float* op0 = out + ((b * 3 + 0) * HH + oy) * WW + ox;
    float* op1 = out + ((b * 3 + 1) * HH + oy) * WW + ox;
    float* op2 = out + ((b * 3 + 2) * HH + oy) * WW + ox;
    float4 o0, o1, o2;
    o0.x = ac0[0] * rw[0]; o0.y = ac0[1] * rw[1]; o0.z = ac0[2] * rw[2]; o0.w = ac0[3] * rw[3];
    o1.x = ac1[0] * rw[0]; o1.y = ac1[1] * rw[1]; o1.z = ac1[2] * rw[2]; o1.w = ac1[3] * rw[3];
    o2.x = ac2[0] * rw[0]; o2.y = ac2[1] * rw[1]; o2.z = ac2[2] * rw[2]; o2.w = ac2[3] * rw[3];
    *(float4*)op0 = o0;
    *(float4*)op1 = o1;
    *(float4*)op2 = o2;
  }
}

extern "C" void kernel_launch(void* const* d_in, const int* in_sizes, int n_in,
                              void* d_out, int out_size, void* d_ws, size_t ws_size,
                              hipStream_t stream) {
  const float* img = (const float*)d_in[0];   // (2,3,512,512) f32
  const float* def = (const float*)d_in[1];   // (2,1,512,512) f32
  float* out = (float*)d_out;                 // (2,3,512,512) f32

  dim3 grid(WW / TW, HH / TH, NB);            // 16 x 32 x 2 = 1024 = 4/CU
  dim3 block(512);
  hipLaunchKernelGGL(bokeh_gather, grid, block, 0, stream, img, def, out);
}

// Round 15
// 16.848 us; speedup vs baseline: 4.1796x; 1.2030x over previous
//
#include <hip/hip_runtime.h>
#include <cmath>

// Bokeh render, gather form:
// out[b,c,y,x] = sum_{dy,dx in [-4,4]} w * img[b,c,y-dy,x-dx] / sum w
// w = sigmoid(8*(r_src - dist)) / max(pi*r_src^2,1);  r = |defocus| in [0,4).
// Window mask dropped (outside-window w <= sigma(-8): output shift <2e-5).
// OOB sources: J=1e30, H=0 -> w ~= 1e-30 (effectively exact zero).
//
// R15 = R10 structure (best: 19.4us) + packed-FP32 accumulation.
// Occupancy ladder complete: 2/4/8 waves per SIMD = 20.6/19.4/20.3 us ->
// occupancy exonerated. R11: main ~8.5us VALU-bound (VALUBusy 65%), accum
// = 4 of 6 VALU/tap. CDNA4 v_pk_fma_f32 does 2 f32 FMAs per issue:
//   acc01  += (w,w)*(c0,c1)       [1 pk]
//   acc2w  += (w,w)*(c2,1.0)      [1 pk; folds wsum via w*1.0]
// via ext_vector_type(2) + __builtin_elementwise_fma (backend emits
// v_pk_fma_f32; w-splat encodable via op_sel_hi broadcast). Tap: fma + rcp
// + 2 pk = 4 issue ops (was 6). J|H fold kept (R13-proven numerics).

#define HH 512
#define WW 512
#define NB 2
#define TW 64                     // tile width (16 quads, zero waste)
#define TH 16                     // tile height
#define HALO 4
#define SROWS (TH + 2 * HALO)     // 24
#define LW 72                     // 4 + 64 + 4 = exactly 72 dwords/row

typedef float v2f __attribute__((ext_vector_type(2)));

__device__ __forceinline__ unsigned rtne_hi(float v) {
  // bf16 round-to-nearest-even, result in HIGH 16 bits (low 16 zero).
  unsigned u = __float_as_uint(v);
  u = u + 0x7FFFu + ((u >> 16) & 1u);
  return u & 0xFFFF0000u;
}

__global__ __launch_bounds__(512, 4) void bokeh_gather(
    const float* __restrict__ img,
    const float* __restrict__ def,
    float* __restrict__ out)
{
  __shared__ __align__(16) unsigned sX[SROWS][LW];  // J(hi) | H(lo)   bf16
  __shared__ __align__(16) unsigned sY[SROWS][LW];  // c0(hi) | c1(lo) bf16
  __shared__ __align__(16) unsigned sZ[SROWS][LW];  // c2 truncated f32
  __shared__ float sFd[9][12];                      // exp(8*dist(dy,dx))
  __shared__ __align__(16) float pbuf[256][20];     // group-1 partials

  const int tid = threadIdx.x;
  const int s   = tid >> 8;      // dy-group: 0 -> dy 0..4, 1 -> dy 5..8
  const int t   = tid & 255;
  const int tx  = t & 15;        // 16 lanes * 4 px = 64 cols
  const int ty  = t >> 4;        // 16 rows
  const int bx = blockIdx.x * TW;
  const int by = blockIdx.y * TH;
  const int b  = blockIdx.z;

  if (tid < 81) {
    int dyi = tid / 9, dxi = tid - dyi * 9;
    int dyo = dyi - 4, dxo = dxi - 4;
    float d2 = (float)(dyo * dyo + dxo * dxo);
    sFd[dyi][dxi] = __expf(8.0f * sqrtf(d2));
  }

  const float* dpt = def + b * (HH * WW);
  const float* ipt = img + b * (3 * HH * WW);

  // Stage halo'd tile: 24 rows x 72 cols = 1728 entries / 512 thr.
  for (int idx = tid; idx < SROWS * LW; idx += 512) {
    int ly = idx / LW;
    int lx = idx - ly * LW;
    int sy = by - HALO + ly;
    int sx = bx - HALO + lx;
    unsigned X, Y = 0u, Z = 0u;
    if ((unsigned)sy < (unsigned)HH && (unsigned)sx < (unsigned)WW) {
      int o = sy * WW + sx;
      float r = fabsf(dpt[o]);
      float J  = fmaxf(3.14159265358979f * r * r, 1.0f);
      float Hv = __expf(-8.0f * r) * J;
      X = rtne_hi(J) | (rtne_hi(Hv) >> 16);
      Y = rtne_hi(ipt[o]) | (rtne_hi(ipt[o + HH * WW]) >> 16);
      Z = __float_as_uint(ipt[o + 2 * HH * WW]) & 0xFFFF0000u;
    } else {
      X = rtne_hi(1e30f);        // J huge, H = 0 -> w ~= 1e-30, channels 0
    }
    sX[ly][lx] = X;
    sY[ly][lx] = Y;
    sZ[ly][lx] = Z;
  }
  __syncthreads();

  v2f a01[4] = {{0.f,0.f},{0.f,0.f},{0.f,0.f},{0.f,0.f}};  // (ac0, ac1)
  v2f a2w[4] = {{0.f,0.f},{0.f,0.f},{0.f,0.f},{0.f,0.f}};  // (ac2, wsum)

  const int col0 = 4 * tx;       // window start col (16B aligned)
  const int dy0 = s ? 5 : 0;
  const int dy1 = s ? 9 : 5;

  #pragma unroll 1
  for (int dy = dy0; dy < dy1; ++dy) {
    const int sr = ty + dy;
    float fdr[9];
    #pragma unroll
    for (int x = 0; x < 9; ++x) fdr[x] = sFd[dy][x];

    unsigned Xv[12], Yv[12], Zv[12];
    #pragma unroll
    for (int q = 0; q < 3; ++q) {
      *(uint4*)&Xv[4 * q] = *(const uint4*)(&sX[sr][col0] + 4 * q);
      *(uint4*)&Yv[4 * q] = *(const uint4*)(&sY[sr][col0] + 4 * q);
      *(uint4*)&Zv[4 * q] = *(const uint4*)(&sZ[sr][col0] + 4 * q);
    }
    float Jv[12], Hv[12];
    v2f C01[12], Z1[12];
    #pragma unroll
    for (int j = 0; j < 12; ++j) {
      Jv[j] = __uint_as_float(Xv[j] & 0xFFFF0000u);
      Hv[j] = __uint_as_float(Xv[j] << 16);
      C01[j] = (v2f){__uint_as_float(Yv[j] & 0xFFFF0000u),
                     __uint_as_float(Yv[j] << 16)};
      Z1[j]  = (v2f){__uint_as_float(Zv[j]), 1.0f};
    }

    #pragma unroll
    for (int k = 0; k < 4; ++k) {
      #pragma unroll
      for (int j = k; j < k + 9; ++j) {
        const int xi = j - k;                      // compile-time
        float tden = fmaf(Hv[j], fdr[xi], Jv[j]);  // J + e^{-8r}J e^{8d}
        float w = __builtin_amdgcn_rcpf(tden);     // = Iv * sigmoid
        v2f wp = (v2f){w, w};
        a01[k] = __builtin_elementwise_fma(wp, C01[j], a01[k]);
        a2w[k] = __builtin_elementwise_fma(wp, Z1[j],  a2w[k]);
      }
    }
  }

  // Combine dy-halves: group 1 publishes, group 0 reduces + stores.
  if (s == 1) {
    *(float4*)&pbuf[t][0]  = make_float4(a2w[0].y, a2w[1].y, a2w[2].y, a2w[3].y);
    *(float4*)&pbuf[t][4]  = make_float4(a01[0].x, a01[1].x, a01[2].x, a01[3].x);
    *(float4*)&pbuf[t][8]  = make_float4(a01[0].y, a01[1].y, a01[2].y, a01[3].y);
    *(float4*)&pbuf[t][12] = make_float4(a2w[0].x, a2w[1].x, a2w[2].x, a2w[3].x);
  }
  __syncthreads();
  if (s == 0) {
    float4 v0 = *(const float4*)&pbuf[t][0];
    float4 v1 = *(const float4*)&pbuf[t][4];
    float4 v2 = *(const float4*)&pbuf[t][8];
    float4 v3 = *(const float4*)&pbuf[t][12];
    float wsum[4] = {a2w[0].y + v0.x, a2w[1].y + v0.y,
                     a2w[2].y + v0.z, a2w[3].y + v0.w};
    float ac0[4]  = {a01[0].x + v1.x, a01[1].x + v1.y,
                     a01[2].x + v1.z, a01[3].x + v1.w};
    float ac1[4]  = {a01[0].y + v2.x, a01[1].y + v2.y,
                     a01[2].y + v2.z, a01[3].y + v2.w};
    float ac2[4]  = {a2w[0].x + v3.x, a2w[1].x + v3.y,
                     a2w[2].x + v3.z, a2w[3].x + v3.w};

    const int oy = by + ty;
    const int ox = bx + col0;
    float rw[4];
    #pragma unroll
    for (int k = 0; k < 4; ++k) rw[k] = __builtin_amdgcn_rcpf(wsum[k]);

    float* op0 = out + ((b * 3 + 0) * HH + oy) * WW + ox;
    float* op1 = out + ((b * 3 + 1) * HH + oy) * WW + ox;
    float* op2 = out + ((b * 3 + 2) * HH + oy) * WW + ox;
    float4 o0, o1, o2;
    o0.x = ac0[0] * rw[0]; o0.y = ac0[1] * rw[1]; o0.z = ac0[2] * rw[2]; o0.w = ac0[3] * rw[3];
    o1.x = ac1[0] * rw[0]; o1.y = ac1[1] * rw[1]; o1.z = ac1[2] * rw[2]; o1.w = ac1[3] * rw[3];
    o2.x = ac2[0] * rw[0]; o2.y = ac2[1] * rw[1]; o2.z = ac2[2] * rw[2]; o2.w = ac2[3] * rw[3];
    *(float4*)op0 = o0;
    *(float4*)op1 = o1;
    *(float4*)op2 = o2;
  }
}

extern "C" void kernel_launch(void* const* d_in, const int* in_sizes, int n_in,
                              void* d_out, int out_size, void* d_ws, size_t ws_size,
                              hipStream_t stream) {
  const float* img = (const float*)d_in[0];   // (2,3,512,512) f32
  const float* def = (const float*)d_in[1];   // (2,1,512,512) f32
  float* out = (float*)d_out;                 // (2,3,512,512) f32

  dim3 grid(WW / TW, HH / TH, NB);            // 8 x 32 x 2 = 512 blocks = 2/CU
  dim3 block(512);
  hipLaunchKernelGGL(bokeh_gather, grid, block, 0, stream, img, def, out);
}